// Round 1
// baseline (1615.053 us; speedup 1.0000x reference)
//
#include <hip/hip_runtime.h>
#include <hip/hip_bf16.h>

#define N_NODES 50000
#define N_EDGES 1600000
#define N_CAND  1000
#define N_GRAPHS 50
#define EMB 32
#define L_LAYERS 4

// ws float layout:
//   [0      .. 4095 ]  W1A' (4 layers x 32x32)  (dst-part of W1, BN1-scaled)
//   [4096   .. 8191 ]  W1B' (4 layers x 32x32)  (src-part of W1, BN1-scaled)
//   [8192   .. 12287]  W2'  (4 layers x 32x32)  (BN2-scaled)
//   [12288  .. 12415]  w1e' (4 x 32)            (edge-attr row of W1, scaled)
//   [12416  .. 12543]  C1   (4 x 32)            (folded bias+BN1 shift)
//   [12544  .. 12671]  C2   (4 x 32)            (folded bias+BN2 shift)
//   [12800  .. ]       h0, h1, hA, hB : 4 x (50000*32) floats
#define W1A_OFF 0
#define W1B_OFF 4096
#define W2_OFF  8192
#define WE_OFF  12288
#define C1_OFF  12416
#define C2_OFF  12544
#define H_OFF   12800
#define NODE_F  (N_NODES * EMB)

__global__ void prep_k(const float* __restrict__ W1, const float* __restrict__ b1,
                       const float* __restrict__ g1, const float* __restrict__ be1,
                       const float* __restrict__ m1, const float* __restrict__ v1,
                       const float* __restrict__ W2, const float* __restrict__ b2,
                       const float* __restrict__ g2, const float* __restrict__ be2,
                       const float* __restrict__ m2, const float* __restrict__ v2,
                       float* __restrict__ ws) {
    int t = threadIdx.x;  // 256 threads, 1 block
    for (int l = 0; l < L_LAYERS; ++l) {
        for (int i = t; i < 1024; i += 256) {
            int k = i >> 5, j = i & 31;
            float s1 = g1[l * 32 + j] * rsqrtf(v1[l * 32 + j] + 1e-5f);
            float s2 = g2[l * 32 + j] * rsqrtf(v2[l * 32 + j] + 1e-5f);
            ws[W1A_OFF + l * 1024 + i] = W1[(l * 65 + k) * 32 + j] * s1;
            ws[W1B_OFF + l * 1024 + i] = W1[(l * 65 + 32 + k) * 32 + j] * s1;
            ws[W2_OFF  + l * 1024 + i] = W2[(l * 32 + k) * 32 + j] * s2;
            if (k == 0) {
                ws[WE_OFF + l * 32 + j] = W1[(l * 65 + 64) * 32 + j] * s1;
                ws[C1_OFF + l * 32 + j] = b1[l * 32 + j] * s1 + be1[l * 32 + j] - m1[l * 32 + j] * s1;
                ws[C2_OFF + l * 32 + j] = b2[l * 32 + j] * s2 + be2[l * 32 + j] - m2[l * 32 + j] * s2;
            }
        }
    }
}

__global__ void embed_k(const float* __restrict__ x, const float* __restrict__ Win,
                        const float* __restrict__ bin, float* __restrict__ h) {
    int t = blockIdx.x * blockDim.x + threadIdx.x;
    if (t >= NODE_F) return;
    int n = t >> 5, j = t & 31;
    h[t] = x[2 * n] * Win[j] + x[2 * n + 1] * Win[32 + j] + bin[j];
}

// per-node: hA = h @ W1A' + C1 ; hB = h @ W1B' ; hnext = h (copy, edge kernel accumulates)
__global__ void node_k(const float* __restrict__ h, const float* __restrict__ ws, int l,
                       float* __restrict__ hA, float* __restrict__ hB, float* __restrict__ hnext) {
    __shared__ float sA[1024], sB[1024];
    const float* W1A = ws + W1A_OFF + l * 1024;
    const float* W1B = ws + W1B_OFF + l * 1024;
    for (int i = threadIdx.x; i < 1024; i += blockDim.x) { sA[i] = W1A[i]; sB[i] = W1B[i]; }
    __syncthreads();
    int t = blockIdx.x * blockDim.x + threadIdx.x;
    if (t >= NODE_F) return;
    int j = t & 31;
    float hv = h[t];
    hnext[t] = hv;
    float a = ws[C1_OFF + l * 32 + j];
    float b = 0.f;
#pragma unroll
    for (int k = 0; k < 32; ++k) {
        float hk = __shfl(hv, k, 32);
        a += hk * sA[k * 32 + j];
        b += hk * sB[k * 32 + j];
    }
    hA[t] = a;
    hB[t] = b;
}

// per-edge: u = relu(hA[dst] + hB[src] + ea*w1e') ; t2 = relu(u @ W2' + C2) ; hnext[dst] += t2
// 16 lanes per edge, 2 channels per lane; W2' columns in registers; u broadcast via shfl.
__launch_bounds__(256)
__global__ void edge_k(const int* __restrict__ ei, const float* __restrict__ ea,
                       const float* __restrict__ ws, int l,
                       const float* __restrict__ hA, const float* __restrict__ hB,
                       float* __restrict__ hnext) {
    const int lane = threadIdx.x & 15;
    const int j0 = lane * 2;
    const float* W2p = ws + W2_OFF + l * 1024;
    float2 w2r[32];
#pragma unroll
    for (int k = 0; k < 32; ++k) {
        w2r[k].x = W2p[k * 32 + j0];
        w2r[k].y = W2p[k * 32 + j0 + 1];
    }
    float2 we, c2;
    we.x = ws[WE_OFF + l * 32 + j0];     we.y = ws[WE_OFF + l * 32 + j0 + 1];
    c2.x = ws[C2_OFF + l * 32 + j0];     c2.y = ws[C2_OFF + l * 32 + j0 + 1];

    int group = (blockIdx.x * blockDim.x + threadIdx.x) >> 4;
    int ngroups = (gridDim.x * blockDim.x) >> 4;
    for (int e = group; e < N_EDGES; e += ngroups) {
        int src = ei[e];
        int dst = ei[N_EDGES + e];
        float eav = ea[e];
        float2 ha = *(const float2*)(hA + dst * 32 + j0);
        float2 hb = *(const float2*)(hB + src * 32 + j0);
        float2 u;
        u.x = fmaxf(ha.x + hb.x + eav * we.x, 0.f);
        u.y = fmaxf(ha.y + hb.y + eav * we.y, 0.f);
        float2 acc = c2;
#pragma unroll
        for (int k2 = 0; k2 < 16; ++k2) {
            float ux = __shfl(u.x, k2, 16);
            float uy = __shfl(u.y, k2, 16);
            acc.x += ux * w2r[2 * k2].x + uy * w2r[2 * k2 + 1].x;
            acc.y += ux * w2r[2 * k2].y + uy * w2r[2 * k2 + 1].y;
        }
        acc.x = fmaxf(acc.x, 0.f);
        acc.y = fmaxf(acc.y, 0.f);
        atomicAdd(hnext + dst * 32 + j0, acc.x);
        atomicAdd(hnext + dst * 32 + j0 + 1, acc.y);
    }
}

__global__ void head_k(const float* __restrict__ h, const int* __restrict__ cand,
                       const int* __restrict__ batch, const float* __restrict__ Wout,
                       const float* __restrict__ bout, float* __restrict__ out) {
    __shared__ float Lg[N_CAND];
    __shared__ int Sg[N_CAND];
    __shared__ float smax[N_GRAPHS], slse[N_GRAPHS];
    int t = threadIdx.x;  // 1024
    if (t < N_CAND) {
        int c = cand[t];
        float acc = bout[0];
#pragma unroll
        for (int j = 0; j < 32; ++j) acc += h[c * 32 + j] * Wout[j];
        Lg[t] = acc;
        Sg[t] = batch[c];
    }
    __syncthreads();
    if (t < N_GRAPHS) {
        float m = -1e30f;
        for (int i = 0; i < N_CAND; ++i)
            if (Sg[i] == t) m = fmaxf(m, Lg[i]);
        smax[t] = m;
        float s = 0.f;
        for (int i = 0; i < N_CAND; ++i)
            if (Sg[i] == t) s += expf(Lg[i] - m);
        slse[t] = logf(s);
    }
    __syncthreads();
    if (t < N_CAND) out[t] = Lg[t] - smax[Sg[t]] - slse[Sg[t]];
}

extern "C" void kernel_launch(void* const* d_in, const int* in_sizes, int n_in,
                              void* d_out, int out_size, void* d_ws, size_t ws_size,
                              hipStream_t stream) {
    const float* x    = (const float*)d_in[0];
    const int*   ei   = (const int*)d_in[1];
    const float* eatt = (const float*)d_in[2];
    const int*   cand = (const int*)d_in[3];
    const int*   batch= (const int*)d_in[4];
    const float* Win  = (const float*)d_in[5];
    const float* bin  = (const float*)d_in[6];
    const float* W1   = (const float*)d_in[7];
    const float* b1   = (const float*)d_in[8];
    const float* g1   = (const float*)d_in[9];
    const float* be1  = (const float*)d_in[10];
    const float* m1   = (const float*)d_in[11];
    const float* v1   = (const float*)d_in[12];
    const float* W2   = (const float*)d_in[13];
    const float* b2   = (const float*)d_in[14];
    const float* g2   = (const float*)d_in[15];
    const float* be2  = (const float*)d_in[16];
    const float* m2   = (const float*)d_in[17];
    const float* v2   = (const float*)d_in[18];
    const float* Wout = (const float*)d_in[19];
    const float* bout = (const float*)d_in[20];
    float* out = (float*)d_out;
    float* ws = (float*)d_ws;

    float* h0 = ws + H_OFF;
    float* h1 = ws + H_OFF + NODE_F;
    float* hA = ws + H_OFF + 2 * NODE_F;
    float* hB = ws + H_OFF + 3 * NODE_F;

    prep_k<<<1, 256, 0, stream>>>(W1, b1, g1, be1, m1, v1, W2, b2, g2, be2, m2, v2, ws);
    embed_k<<<(NODE_F + 255) / 256, 256, 0, stream>>>(x, Win, bin, h0);

    float* cur = h0;
    float* nxt = h1;
    for (int l = 0; l < L_LAYERS; ++l) {
        node_k<<<(NODE_F + 255) / 256, 256, 0, stream>>>(cur, ws, l, hA, hB, nxt);
        edge_k<<<2048, 256, 0, stream>>>(ei, eatt, ws, l, hA, hB, nxt);
        float* tmp = cur; cur = nxt; nxt = tmp;
    }

    head_k<<<1, 1024, 0, stream>>>(cur, cand, batch, Wout, bout, out);
}

// Round 2
// 1392.712 us; speedup vs baseline: 1.1596x; 1.1596x over previous
//
#include <hip/hip_runtime.h>
#include <hip/hip_bf16.h>

#define N_NODES 50000
#define N_EDGES 1600000
#define N_CAND  1000
#define N_GRAPHS 50
#define EMB 32
#define L_LAYERS 4

// ws float layout:
//   [0      .. 4095 ]  W1A' (4 layers x 32x32)  (dst-part of W1, BN1-scaled)
//   [4096   .. 8191 ]  W1B' (4 layers x 32x32)  (src-part of W1, BN1-scaled)
//   [8192   .. 12287]  W2'  (4 layers x 32x32)  (BN2-scaled)
//   [12288  .. 12415]  w1e' (4 x 32)
//   [12416  .. 12543]  C1   (4 x 32)
//   [12544  .. 12671]  C2   (4 x 32)
//   [12800  .. ]       h0, h1, hA, hB : 4 x (50000*32) floats
//   then CSR ints/floats (see *_OFF below)
#define W1A_OFF 0
#define W1B_OFF 4096
#define W2_OFF  8192
#define WE_OFF  12288
#define C1_OFF  12416
#define C2_OFF  12544
#define H_OFF   12800
#define NODE_F  (N_NODES * EMB)

#define DEG_OFF   (H_OFF + 4 * NODE_F)            // int[N_NODES]
#define OFFS_OFF  (DEG_OFF + N_NODES)             // int[N_NODES+1]
#define CUR_OFF   (OFFS_OFF + N_NODES + 1)        // int[N_NODES]
#define SRCS_OFF  (CUR_OFF + N_NODES)             // int[N_EDGES]
#define EAS_OFF   (SRCS_OFF + N_EDGES)            // float[N_EDGES]

__global__ void prep_k(const float* __restrict__ W1, const float* __restrict__ b1,
                       const float* __restrict__ g1, const float* __restrict__ be1,
                       const float* __restrict__ m1, const float* __restrict__ v1,
                       const float* __restrict__ W2, const float* __restrict__ b2,
                       const float* __restrict__ g2, const float* __restrict__ be2,
                       const float* __restrict__ m2, const float* __restrict__ v2,
                       float* __restrict__ ws) {
    int t = threadIdx.x;  // 256 threads, 1 block
    for (int l = 0; l < L_LAYERS; ++l) {
        for (int i = t; i < 1024; i += 256) {
            int k = i >> 5, j = i & 31;
            float s1 = g1[l * 32 + j] * rsqrtf(v1[l * 32 + j] + 1e-5f);
            float s2 = g2[l * 32 + j] * rsqrtf(v2[l * 32 + j] + 1e-5f);
            ws[W1A_OFF + l * 1024 + i] = W1[(l * 65 + k) * 32 + j] * s1;
            ws[W1B_OFF + l * 1024 + i] = W1[(l * 65 + 32 + k) * 32 + j] * s1;
            ws[W2_OFF  + l * 1024 + i] = W2[(l * 32 + k) * 32 + j] * s2;
            if (k == 0) {
                ws[WE_OFF + l * 32 + j] = W1[(l * 65 + 64) * 32 + j] * s1;
                ws[C1_OFF + l * 32 + j] = b1[l * 32 + j] * s1 + be1[l * 32 + j] - m1[l * 32 + j] * s1;
                ws[C2_OFF + l * 32 + j] = b2[l * 32 + j] * s2 + be2[l * 32 + j] - m2[l * 32 + j] * s2;
            }
        }
    }
}

__global__ void embed_k(const float* __restrict__ x, const float* __restrict__ Win,
                        const float* __restrict__ bin, float* __restrict__ h) {
    int t = blockIdx.x * blockDim.x + threadIdx.x;
    if (t >= NODE_F) return;
    int n = t >> 5, j = t & 31;
    h[t] = x[2 * n] * Win[j] + x[2 * n + 1] * Win[32 + j] + bin[j];
}

// ---------------- CSR build ----------------
__global__ void zero_k(int* __restrict__ p, int n) {
    int t = blockIdx.x * blockDim.x + threadIdx.x;
    if (t < n) p[t] = 0;
}

__global__ void hist_k(const int* __restrict__ ei, int* __restrict__ deg) {
    int e = blockIdx.x * blockDim.x + threadIdx.x;
    if (e < N_EDGES) atomicAdd(&deg[ei[N_EDGES + e]], 1);
}

// single block, 1024 threads: exclusive scan of deg -> off, cursor
__global__ void scan_k(const int* __restrict__ deg, int* __restrict__ off,
                       int* __restrict__ cursor) {
    __shared__ int part[1024];
    const int CH = (N_NODES + 1023) / 1024;
    int t = threadIdx.x;
    int base = t * CH;
    int s = 0;
    for (int i = 0; i < CH; ++i) {
        int idx = base + i;
        if (idx < N_NODES) s += deg[idx];
    }
    part[t] = s;
    __syncthreads();
    for (int d = 1; d < 1024; d <<= 1) {
        int v = (t >= d) ? part[t - d] : 0;
        __syncthreads();
        part[t] += v;
        __syncthreads();
    }
    int run = part[t] - s;  // exclusive prefix
    for (int i = 0; i < CH; ++i) {
        int idx = base + i;
        if (idx < N_NODES) {
            off[idx] = run;
            cursor[idx] = run;
            run += deg[idx];
        }
    }
    if (t == 1023) off[N_NODES] = run;
}

__global__ void scatter_k(const int* __restrict__ ei, const float* __restrict__ ea,
                          int* __restrict__ cursor, int* __restrict__ srcs,
                          float* __restrict__ eas) {
    int e = blockIdx.x * blockDim.x + threadIdx.x;
    if (e >= N_EDGES) return;
    int dst = ei[N_EDGES + e];
    int pos = atomicAdd(&cursor[dst], 1);
    srcs[pos] = ei[e];
    eas[pos] = ea[e];
}

// ---------------- per-layer kernels ----------------
// per-node: hA = h @ W1A' + C1 ; hB = h @ W1B'
__global__ void node_k(const float* __restrict__ h, const float* __restrict__ ws, int l,
                       float* __restrict__ hA, float* __restrict__ hB) {
    __shared__ float sA[1024], sB[1024];
    const float* W1A = ws + W1A_OFF + l * 1024;
    const float* W1B = ws + W1B_OFF + l * 1024;
    for (int i = threadIdx.x; i < 1024; i += blockDim.x) { sA[i] = W1A[i]; sB[i] = W1B[i]; }
    __syncthreads();
    int t = blockIdx.x * blockDim.x + threadIdx.x;
    if (t >= NODE_F) return;
    int j = t & 31;
    float hv = h[t];
    float a = ws[C1_OFF + l * 32 + j];
    float b = 0.f;
#pragma unroll
    for (int k = 0; k < 32; ++k) {
        float hk = __shfl(hv, k, 32);
        a += hk * sA[k * 32 + j];
        b += hk * sB[k * 32 + j];
    }
    hA[t] = a;
    hB[t] = b;
}

// node-centric edge aggregation: 16 lanes per node, 2 channels per lane.
// acc = h[node]; for each in-edge: u = relu(hA[node]+hB[src]+ea*we);
// acc += relu(u @ W2' + C2); write hnext[node] = acc. No atomics.
__launch_bounds__(256)
__global__ void edge_nc_k(const int* __restrict__ offs, const int* __restrict__ srcs,
                          const float* __restrict__ eas, const float* __restrict__ ws, int l,
                          const float* __restrict__ h, const float* __restrict__ hA,
                          const float* __restrict__ hB, float* __restrict__ hnext) {
    const int lane = threadIdx.x & 15;
    const int j0 = lane * 2;
    const int n = blockIdx.x * 16 + (threadIdx.x >> 4);
    const float* W2p = ws + W2_OFF + l * 1024;
    float2 w2r[32];
#pragma unroll
    for (int k = 0; k < 32; ++k) {
        w2r[k].x = W2p[k * 32 + j0];
        w2r[k].y = W2p[k * 32 + j0 + 1];
    }
    float2 we, c2;
    we.x = ws[WE_OFF + l * 32 + j0];  we.y = ws[WE_OFF + l * 32 + j0 + 1];
    c2.x = ws[C2_OFF + l * 32 + j0];  c2.y = ws[C2_OFF + l * 32 + j0 + 1];
    if (n >= N_NODES) return;

    float2 acc = *(const float2*)(h + n * 32 + j0);
    float2 hav = *(const float2*)(hA + n * 32 + j0);
    const int beg = offs[n], end = offs[n + 1];

    int k = beg;
#define EDGE_BODY(HB, EAV)                                                   \
    {                                                                        \
        float2 u;                                                            \
        u.x = fmaxf(hav.x + (HB).x + (EAV) * we.x, 0.f);                     \
        u.y = fmaxf(hav.y + (HB).y + (EAV) * we.y, 0.f);                     \
        float2 t2 = c2;                                                      \
        _Pragma("unroll")                                                    \
        for (int k2 = 0; k2 < 16; ++k2) {                                    \
            float ux = __shfl(u.x, k2, 16);                                  \
            float uy = __shfl(u.y, k2, 16);                                  \
            t2.x += ux * w2r[2 * k2].x + uy * w2r[2 * k2 + 1].x;             \
            t2.y += ux * w2r[2 * k2].y + uy * w2r[2 * k2 + 1].y;             \
        }                                                                    \
        acc.x += fmaxf(t2.x, 0.f);                                           \
        acc.y += fmaxf(t2.y, 0.f);                                           \
    }

    for (; k + 2 <= end; k += 2) {
        int s0 = srcs[k], s1 = srcs[k + 1];
        float e0 = eas[k], e1 = eas[k + 1];
        float2 hb0 = *(const float2*)(hB + s0 * 32 + j0);
        float2 hb1 = *(const float2*)(hB + s1 * 32 + j0);
        EDGE_BODY(hb0, e0);
        EDGE_BODY(hb1, e1);
    }
    if (k < end) {
        int s0 = srcs[k];
        float e0 = eas[k];
        float2 hb0 = *(const float2*)(hB + s0 * 32 + j0);
        EDGE_BODY(hb0, e0);
    }
#undef EDGE_BODY
    *(float2*)(hnext + n * 32 + j0) = acc;
}

__global__ void head_k(const float* __restrict__ h, const int* __restrict__ cand,
                       const int* __restrict__ batch, const float* __restrict__ Wout,
                       const float* __restrict__ bout, float* __restrict__ out) {
    __shared__ float Lg[N_CAND];
    __shared__ int Sg[N_CAND];
    __shared__ float smax[N_GRAPHS], slse[N_GRAPHS];
    int t = threadIdx.x;  // 1024
    if (t < N_CAND) {
        int c = cand[t];
        float acc = bout[0];
#pragma unroll
        for (int j = 0; j < 32; ++j) acc += h[c * 32 + j] * Wout[j];
        Lg[t] = acc;
        Sg[t] = batch[c];
    }
    __syncthreads();
    if (t < N_GRAPHS) {
        float m = -1e30f;
        for (int i = 0; i < N_CAND; ++i)
            if (Sg[i] == t) m = fmaxf(m, Lg[i]);
        smax[t] = m;
        float s = 0.f;
        for (int i = 0; i < N_CAND; ++i)
            if (Sg[i] == t) s += expf(Lg[i] - m);
        slse[t] = logf(s);
    }
    __syncthreads();
    if (t < N_CAND) out[t] = Lg[t] - smax[Sg[t]] - slse[Sg[t]];
}

extern "C" void kernel_launch(void* const* d_in, const int* in_sizes, int n_in,
                              void* d_out, int out_size, void* d_ws, size_t ws_size,
                              hipStream_t stream) {
    const float* x    = (const float*)d_in[0];
    const int*   ei   = (const int*)d_in[1];
    const float* eatt = (const float*)d_in[2];
    const int*   cand = (const int*)d_in[3];
    const int*   batch= (const int*)d_in[4];
    const float* Win  = (const float*)d_in[5];
    const float* bin  = (const float*)d_in[6];
    const float* W1   = (const float*)d_in[7];
    const float* b1   = (const float*)d_in[8];
    const float* g1   = (const float*)d_in[9];
    const float* be1  = (const float*)d_in[10];
    const float* m1   = (const float*)d_in[11];
    const float* v1   = (const float*)d_in[12];
    const float* W2   = (const float*)d_in[13];
    const float* b2   = (const float*)d_in[14];
    const float* g2   = (const float*)d_in[15];
    const float* be2  = (const float*)d_in[16];
    const float* m2   = (const float*)d_in[17];
    const float* v2   = (const float*)d_in[18];
    const float* Wout = (const float*)d_in[19];
    const float* bout = (const float*)d_in[20];
    float* out = (float*)d_out;
    float* ws = (float*)d_ws;

    float* h0 = ws + H_OFF;
    float* h1 = ws + H_OFF + NODE_F;
    float* hA = ws + H_OFF + 2 * NODE_F;
    float* hB = ws + H_OFF + 3 * NODE_F;
    int* deg    = (int*)(ws + DEG_OFF);
    int* offs   = (int*)(ws + OFFS_OFF);
    int* cursor = (int*)(ws + CUR_OFF);
    int* srcs   = (int*)(ws + SRCS_OFF);
    float* eas  = ws + EAS_OFF;

    prep_k<<<1, 256, 0, stream>>>(W1, b1, g1, be1, m1, v1, W2, b2, g2, be2, m2, v2, ws);
    embed_k<<<(NODE_F + 255) / 256, 256, 0, stream>>>(x, Win, bin, h0);

    // CSR build (dst-sorted)
    zero_k<<<(N_NODES + 255) / 256, 256, 0, stream>>>(deg, N_NODES);
    hist_k<<<(N_EDGES + 255) / 256, 256, 0, stream>>>(ei, deg);
    scan_k<<<1, 1024, 0, stream>>>(deg, offs, cursor);
    scatter_k<<<(N_EDGES + 255) / 256, 256, 0, stream>>>(ei, eatt, cursor, srcs, eas);

    float* cur = h0;
    float* nxt = h1;
    for (int l = 0; l < L_LAYERS; ++l) {
        node_k<<<(NODE_F + 255) / 256, 256, 0, stream>>>(cur, ws, l, hA, hB);
        edge_nc_k<<<(N_NODES + 15) / 16, 256, 0, stream>>>(offs, srcs, eas, ws, l,
                                                           cur, hA, hB, nxt);
        float* tmp = cur; cur = nxt; nxt = tmp;
    }

    head_k<<<1, 1024, 0, stream>>>(cur, cand, batch, Wout, bout, out);
}

// Round 3
// 623.357 us; speedup vs baseline: 2.5909x; 2.2342x over previous
//
#include <hip/hip_runtime.h>
#include <hip/hip_bf16.h>

#define N_NODES 50000
#define N_EDGES 1600000
#define N_CAND  1000
#define N_GRAPHS 50
#define EMB 32
#define L_LAYERS 4

#define W1A_OFF 0
#define W1B_OFF 4096
#define W2_OFF  8192
#define WE_OFF  12288
#define C1_OFF  12416
#define C2_OFF  12544
#define H_OFF   12800
#define NODE_F  (N_NODES * EMB)

#define DEG_OFF   (H_OFF + 4 * NODE_F)            // int[N_NODES]
#define OFFS_OFF  (DEG_OFF + N_NODES)             // int[N_NODES+1]
#define CUR_OFF   (OFFS_OFF + N_NODES + 1)        // int[N_NODES]
#define SRCS_OFF  (CUR_OFF + N_NODES)             // int[N_EDGES]
#define EAS_OFF   (SRCS_OFF + N_EDGES)            // float[N_EDGES]

typedef float f32x4 __attribute__((ext_vector_type(4)));
typedef __bf16 bf16x8 __attribute__((ext_vector_type(8)));
union BF8 { unsigned short us[8]; bf16x8 v; };

static __device__ __forceinline__ unsigned short f2bf(float f) {
    unsigned u = __builtin_bit_cast(unsigned, f);
    u += 0x7FFFu + ((u >> 16) & 1u);   // round-to-nearest-even
    return (unsigned short)(u >> 16);
}

__global__ void prep_k(const float* __restrict__ W1, const float* __restrict__ b1,
                       const float* __restrict__ g1, const float* __restrict__ be1,
                       const float* __restrict__ m1, const float* __restrict__ v1,
                       const float* __restrict__ W2, const float* __restrict__ b2,
                       const float* __restrict__ g2, const float* __restrict__ be2,
                       const float* __restrict__ m2, const float* __restrict__ v2,
                       float* __restrict__ ws) {
    int t = threadIdx.x;  // 256 threads, 1 block
    for (int l = 0; l < L_LAYERS; ++l) {
        for (int i = t; i < 1024; i += 256) {
            int k = i >> 5, j = i & 31;
            float s1 = g1[l * 32 + j] * rsqrtf(v1[l * 32 + j] + 1e-5f);
            float s2 = g2[l * 32 + j] * rsqrtf(v2[l * 32 + j] + 1e-5f);
            ws[W1A_OFF + l * 1024 + i] = W1[(l * 65 + k) * 32 + j] * s1;
            ws[W1B_OFF + l * 1024 + i] = W1[(l * 65 + 32 + k) * 32 + j] * s1;
            ws[W2_OFF  + l * 1024 + i] = W2[(l * 32 + k) * 32 + j] * s2;
            if (k == 0) {
                ws[WE_OFF + l * 32 + j] = W1[(l * 65 + 64) * 32 + j] * s1;
                ws[C1_OFF + l * 32 + j] = b1[l * 32 + j] * s1 + be1[l * 32 + j] - m1[l * 32 + j] * s1;
                ws[C2_OFF + l * 32 + j] = b2[l * 32 + j] * s2 + be2[l * 32 + j] - m2[l * 32 + j] * s2;
            }
        }
    }
}

__global__ void embed_k(const float* __restrict__ x, const float* __restrict__ Win,
                        const float* __restrict__ bin, float* __restrict__ h) {
    int t = blockIdx.x * blockDim.x + threadIdx.x;
    if (t >= NODE_F) return;
    int n = t >> 5, j = t & 31;
    h[t] = x[2 * n] * Win[j] + x[2 * n + 1] * Win[32 + j] + bin[j];
}

// ---------------- CSR build ----------------
__global__ void zero_k(int* __restrict__ p, int n) {
    int t = blockIdx.x * blockDim.x + threadIdx.x;
    if (t < n) p[t] = 0;
}

__global__ void hist_k(const int* __restrict__ ei, int* __restrict__ deg) {
    int e = blockIdx.x * blockDim.x + threadIdx.x;
    if (e < N_EDGES) atomicAdd(&deg[ei[N_EDGES + e]], 1);
}

__global__ void scan_k(const int* __restrict__ deg, int* __restrict__ off,
                       int* __restrict__ cursor) {
    __shared__ int part[1024];
    const int CH = (N_NODES + 1023) / 1024;
    int t = threadIdx.x;
    int base = t * CH;
    int s = 0;
    for (int i = 0; i < CH; ++i) {
        int idx = base + i;
        if (idx < N_NODES) s += deg[idx];
    }
    part[t] = s;
    __syncthreads();
    for (int d = 1; d < 1024; d <<= 1) {
        int v = (t >= d) ? part[t - d] : 0;
        __syncthreads();
        part[t] += v;
        __syncthreads();
    }
    int run = part[t] - s;  // exclusive prefix
    for (int i = 0; i < CH; ++i) {
        int idx = base + i;
        if (idx < N_NODES) {
            off[idx] = run;
            cursor[idx] = run;
            run += deg[idx];
        }
    }
    if (t == 1023) off[N_NODES] = run;
}

__global__ void scatter_k(const int* __restrict__ ei, const float* __restrict__ ea,
                          int* __restrict__ cursor, int* __restrict__ srcs,
                          float* __restrict__ eas) {
    int e = blockIdx.x * blockDim.x + threadIdx.x;
    if (e >= N_EDGES) return;
    int dst = ei[N_EDGES + e];
    int pos = atomicAdd(&cursor[dst], 1);
    srcs[pos] = ei[e];
    eas[pos] = ea[e];
}

// ---------------- per-layer kernels ----------------
__global__ void node_k(const float* __restrict__ h, const float* __restrict__ ws, int l,
                       float* __restrict__ hA, float* __restrict__ hB) {
    __shared__ float sA[1024], sB[1024];
    const float* W1A = ws + W1A_OFF + l * 1024;
    const float* W1B = ws + W1B_OFF + l * 1024;
    for (int i = threadIdx.x; i < 1024; i += blockDim.x) { sA[i] = W1A[i]; sB[i] = W1B[i]; }
    __syncthreads();
    int t = blockIdx.x * blockDim.x + threadIdx.x;
    if (t >= NODE_F) return;
    int j = t & 31;
    float hv = h[t];
    float a = ws[C1_OFF + l * 32 + j];
    float b = 0.f;
#pragma unroll
    for (int k = 0; k < 32; ++k) {
        float hk = __shfl(hv, k, 32);
        a += hk * sA[k * 32 + j];
        b += hk * sB[k * 32 + j];
    }
    hA[t] = a;
    hB[t] = b;
}

// One wave per node. Chunks of 16 in-edges -> U[16x32] bf16 in regs ->
// mfma_f32_16x16x32_bf16 against W2' halves -> relu(+C2), predicated row sum.
// A frag: lane l = row l&15, k = 8*(l>>4)+i. C/D: col=lane&15, row=4*(lane>>4)+reg.
__launch_bounds__(256)
__global__ void edge_mfma_k(const int* __restrict__ offs, const int* __restrict__ srcs,
                            const float* __restrict__ eas, const float* __restrict__ ws, int l,
                            const float* __restrict__ h, const float* __restrict__ hA,
                            const float* __restrict__ hB, float* __restrict__ hnext) {
    const int lane = threadIdx.x & 63;
    const int n = blockIdx.x * 4 + (threadIdx.x >> 6);
    if (n >= N_NODES) return;
    const int r = lane & 15;   // A row / D col
    const int q = lane >> 4;   // channel octet

    const float* W2p = ws + W2_OFF + l * 1024;
    BF8 b0, b1;
#pragma unroll
    for (int i = 0; i < 8; ++i) {
        b0.us[i] = f2bf(W2p[(8 * q + i) * 32 + r]);
        b1.us[i] = f2bf(W2p[(8 * q + i) * 32 + 16 + r]);
    }
    const float c2a = ws[C2_OFF + l * 32 + r];
    const float c2b = ws[C2_OFF + l * 32 + 16 + r];
    const f32x4 hA0 = *(const f32x4*)(hA + n * 32 + 8 * q);
    const f32x4 hA1 = *(const f32x4*)(hA + n * 32 + 8 * q + 4);
    const f32x4 we0 = *(const f32x4*)(ws + WE_OFF + l * 32 + 8 * q);
    const f32x4 we1 = *(const f32x4*)(ws + WE_OFF + l * 32 + 8 * q + 4);

    const int beg = offs[n], end = offs[n + 1];
    float ns0 = 0.f, ns1 = 0.f;

    for (int ebase = beg; ebase < end; ebase += 16) {
        int e = ebase + r;
        int ec = (e < end) ? e : (end - 1);
        int src = srcs[ec];
        float eav = eas[ec];
        const f32x4 hb0 = *(const f32x4*)(hB + src * 32 + 8 * q);
        const f32x4 hb1 = *(const f32x4*)(hB + src * 32 + 8 * q + 4);
        BF8 a;
#pragma unroll
        for (int i = 0; i < 4; ++i) {
            float u0 = fmaxf(hA0[i] + hb0[i] + eav * we0[i], 0.f);
            float u1 = fmaxf(hA1[i] + hb1[i] + eav * we1[i], 0.f);
            a.us[i]     = f2bf(u0);
            a.us[i + 4] = f2bf(u1);
        }
        f32x4 z = {0.f, 0.f, 0.f, 0.f};
        f32x4 acc0 = __builtin_amdgcn_mfma_f32_16x16x32_bf16(a.v, b0.v, z, 0, 0, 0);
        f32x4 acc1 = __builtin_amdgcn_mfma_f32_16x16x32_bf16(a.v, b1.v, z, 0, 0, 0);
        int nreal = end - ebase;
#pragma unroll
        for (int reg = 0; reg < 4; ++reg) {
            int row = 4 * q + reg;
            float t0 = fmaxf(acc0[reg] + c2a, 0.f);
            float t1 = fmaxf(acc1[reg] + c2b, 0.f);
            ns0 += (row < nreal) ? t0 : 0.f;
            ns1 += (row < nreal) ? t1 : 0.f;
        }
    }
    ns0 += __shfl_xor(ns0, 16, 64);
    ns0 += __shfl_xor(ns0, 32, 64);
    ns1 += __shfl_xor(ns1, 16, 64);
    ns1 += __shfl_xor(ns1, 32, 64);
    if (lane < 32) {
        float base = h[n * 32 + lane];
        hnext[n * 32 + lane] = base + ((lane & 16) ? ns1 : ns0);
    }
}

__global__ void head_k(const float* __restrict__ h, const int* __restrict__ cand,
                       const int* __restrict__ batch, const float* __restrict__ Wout,
                       const float* __restrict__ bout, float* __restrict__ out) {
    __shared__ float Lg[N_CAND];
    __shared__ int Sg[N_CAND];
    __shared__ float gm[N_GRAPHS], gs[N_GRAPHS];
    int t = threadIdx.x;  // 1024
    if (t < N_CAND) {
        int c = cand[t];
        float acc = bout[0];
#pragma unroll
        for (int j = 0; j < 32; ++j) acc += h[c * 32 + j] * Wout[j];
        Lg[t] = acc;
        Sg[t] = batch[c];
    }
    __syncthreads();
    if (t < 16 * N_GRAPHS) {
        int g = t >> 4, s = t & 15;
        float m = -1e30f;
        for (int i = s; i < N_CAND; i += 16)
            if (Sg[i] == g) m = fmaxf(m, Lg[i]);
#pragma unroll
        for (int d = 1; d < 16; d <<= 1) m = fmaxf(m, __shfl_xor(m, d, 64));
        float ssum = 0.f;
        for (int i = s; i < N_CAND; i += 16)
            if (Sg[i] == g) ssum += expf(Lg[i] - m);
#pragma unroll
        for (int d = 1; d < 16; d <<= 1) ssum += __shfl_xor(ssum, d, 64);
        if (s == 0) { gm[g] = m; gs[g] = logf(ssum); }
    }
    __syncthreads();
    if (t < N_CAND) out[t] = Lg[t] - gm[Sg[t]] - gs[Sg[t]];
}

extern "C" void kernel_launch(void* const* d_in, const int* in_sizes, int n_in,
                              void* d_out, int out_size, void* d_ws, size_t ws_size,
                              hipStream_t stream) {
    const float* x    = (const float*)d_in[0];
    const int*   ei   = (const int*)d_in[1];
    const float* eatt = (const float*)d_in[2];
    const int*   cand = (const int*)d_in[3];
    const int*   batch= (const int*)d_in[4];
    const float* Win  = (const float*)d_in[5];
    const float* bin  = (const float*)d_in[6];
    const float* W1   = (const float*)d_in[7];
    const float* b1   = (const float*)d_in[8];
    const float* g1   = (const float*)d_in[9];
    const float* be1  = (const float*)d_in[10];
    const float* m1   = (const float*)d_in[11];
    const float* v1   = (const float*)d_in[12];
    const float* W2   = (const float*)d_in[13];
    const float* b2   = (const float*)d_in[14];
    const float* g2   = (const float*)d_in[15];
    const float* be2  = (const float*)d_in[16];
    const float* m2   = (const float*)d_in[17];
    const float* v2   = (const float*)d_in[18];
    const float* Wout = (const float*)d_in[19];
    const float* bout = (const float*)d_in[20];
    float* out = (float*)d_out;
    float* ws = (float*)d_ws;

    float* h0 = ws + H_OFF;
    float* h1 = ws + H_OFF + NODE_F;
    float* hA = ws + H_OFF + 2 * NODE_F;
    float* hB = ws + H_OFF + 3 * NODE_F;
    int* deg    = (int*)(ws + DEG_OFF);
    int* offs   = (int*)(ws + OFFS_OFF);
    int* cursor = (int*)(ws + CUR_OFF);
    int* srcs   = (int*)(ws + SRCS_OFF);
    float* eas  = ws + EAS_OFF;

    prep_k<<<1, 256, 0, stream>>>(W1, b1, g1, be1, m1, v1, W2, b2, g2, be2, m2, v2, ws);
    embed_k<<<(NODE_F + 255) / 256, 256, 0, stream>>>(x, Win, bin, h0);

    zero_k<<<(N_NODES + 255) / 256, 256, 0, stream>>>(deg, N_NODES);
    hist_k<<<(N_EDGES + 255) / 256, 256, 0, stream>>>(ei, deg);
    scan_k<<<1, 1024, 0, stream>>>(deg, offs, cursor);
    scatter_k<<<(N_EDGES + 255) / 256, 256, 0, stream>>>(ei, eatt, cursor, srcs, eas);

    float* cur = h0;
    float* nxt = h1;
    for (int l = 0; l < L_LAYERS; ++l) {
        node_k<<<(NODE_F + 255) / 256, 256, 0, stream>>>(cur, ws, l, hA, hB);
        edge_mfma_k<<<(N_NODES + 3) / 4, 256, 0, stream>>>(offs, srcs, eas, ws, l,
                                                           cur, hA, hB, nxt);
        float* tmp = cur; cur = nxt; nxt = tmp;
    }

    head_k<<<1, 1024, 0, stream>>>(cur, cand, batch, Wout, bout, out);
}

// Round 4
// 527.290 us; speedup vs baseline: 3.0629x; 1.1822x over previous
//
#include <hip/hip_runtime.h>
#include <hip/hip_bf16.h>

#define N_NODES 50000
#define N_EDGES 1600000
#define N_CAND  1000
#define N_GRAPHS 50
#define EMB 32
#define L_LAYERS 4
#define NB ((N_NODES + 127) >> 7)   // 391 buckets of 128 nodes

#define W1A_OFF 0
#define W1B_OFF 4096
#define W2_OFF  8192
#define WE_OFF  12288
#define C1_OFF  12416
#define C2_OFF  12544
#define H_OFF   12800
#define NODE_F  (N_NODES * EMB)

// int scratch after the h buffers
#define DEG_OFF   (H_OFF + 4 * NODE_F)                 // int[N_NODES]
#define OFFS_OFF  (DEG_OFF + N_NODES)                  // int[N_NODES+1]
#define CUR_OFF   (OFFS_OFF + N_NODES + 1)             // int[N_NODES]
#define PART_OFF  (CUR_OFF + N_NODES)                  // int[64] scan partials
#define BCUR_OFF  (((PART_OFF + 64) + 15) & ~15)       // int[NB*16] padded cursors (64B/line)
#define CSR_OFF   (((BCUR_OFF + 16 * NB) + 1) & ~1)    // int2[N_EDGES]
// bedge staging (int2[N_EDGES] = 12.8MB) aliases hA/hB region (used before node_k runs)

typedef float f32x4 __attribute__((ext_vector_type(4)));
typedef __bf16 bf16x8 __attribute__((ext_vector_type(8)));
union BF8 { unsigned short us[8]; bf16x8 v; };

static __device__ __forceinline__ unsigned short f2bf(float f) {
    unsigned u = __builtin_bit_cast(unsigned, f);
    u += 0x7FFFu + ((u >> 16) & 1u);   // round-to-nearest-even
    return (unsigned short)(u >> 16);
}

__global__ void prep_k(const float* __restrict__ W1, const float* __restrict__ b1,
                       const float* __restrict__ g1, const float* __restrict__ be1,
                       const float* __restrict__ m1, const float* __restrict__ v1,
                       const float* __restrict__ W2, const float* __restrict__ b2,
                       const float* __restrict__ g2, const float* __restrict__ be2,
                       const float* __restrict__ m2, const float* __restrict__ v2,
                       float* __restrict__ ws) {
    int t = threadIdx.x;  // 256 threads, 1 block
    for (int l = 0; l < L_LAYERS; ++l) {
        for (int i = t; i < 1024; i += 256) {
            int k = i >> 5, j = i & 31;
            float s1 = g1[l * 32 + j] * rsqrtf(v1[l * 32 + j] + 1e-5f);
            float s2 = g2[l * 32 + j] * rsqrtf(v2[l * 32 + j] + 1e-5f);
            ws[W1A_OFF + l * 1024 + i] = W1[(l * 65 + k) * 32 + j] * s1;
            ws[W1B_OFF + l * 1024 + i] = W1[(l * 65 + 32 + k) * 32 + j] * s1;
            ws[W2_OFF  + l * 1024 + i] = W2[(l * 32 + k) * 32 + j] * s2;
            if (k == 0) {
                ws[WE_OFF + l * 32 + j] = W1[(l * 65 + 64) * 32 + j] * s1;
                ws[C1_OFF + l * 32 + j] = b1[l * 32 + j] * s1 + be1[l * 32 + j] - m1[l * 32 + j] * s1;
                ws[C2_OFF + l * 32 + j] = b2[l * 32 + j] * s2 + be2[l * 32 + j] - m2[l * 32 + j] * s2;
            }
        }
    }
}

__global__ void embed_k(const float* __restrict__ x, const float* __restrict__ Win,
                        const float* __restrict__ bin, float* __restrict__ h) {
    int t = blockIdx.x * blockDim.x + threadIdx.x;
    if (t >= NODE_F) return;
    int n = t >> 5, j = t & 31;
    h[t] = x[2 * n] * Win[j] + x[2 * n + 1] * Win[32 + j] + bin[j];
}

// ---------------- CSR build ----------------
__global__ void zero_k(int* __restrict__ p, int n) {
    int t = blockIdx.x * blockDim.x + threadIdx.x;
    if (t < n) p[t] = 0;
}

__global__ void hist_k(const int* __restrict__ ei, int* __restrict__ deg) {
    int e = blockIdx.x * blockDim.x + threadIdx.x;
    if (e < N_EDGES) atomicAdd(&deg[ei[N_EDGES + e]], 1);
}

// hierarchical exclusive scan of deg[50000] -> offs, cursor
__global__ void scan1_k(const int* __restrict__ deg, int* __restrict__ offs,
                        int* __restrict__ part) {
    __shared__ int sh[1024];
    int t = threadIdx.x, idx = blockIdx.x * 1024 + t;
    int v = (idx < N_NODES) ? deg[idx] : 0;
    sh[t] = v;
    __syncthreads();
    for (int d = 1; d < 1024; d <<= 1) {
        int u = (t >= d) ? sh[t - d] : 0;
        __syncthreads();
        sh[t] += u;
        __syncthreads();
    }
    if (idx < N_NODES) offs[idx] = sh[t] - v;   // local exclusive
    if (t == 1023) part[blockIdx.x] = sh[t];
}

__global__ void scan2_k(int* __restrict__ part, int nb) {
    if (threadIdx.x == 0) {
        int run = 0;
        for (int i = 0; i < nb; ++i) { int v = part[i]; part[i] = run; run += v; }
    }
}

__global__ void scan3_k(int* __restrict__ offs, const int* __restrict__ part,
                        int* __restrict__ cursor) {
    int idx = blockIdx.x * 1024 + threadIdx.x;
    if (idx < N_NODES) {
        int o = offs[idx] + part[blockIdx.x];
        offs[idx] = o;
        cursor[idx] = o;
    }
    if (idx == 0) offs[N_NODES] = N_EDGES;
}

__global__ void binit_k(const int* __restrict__ offs, int* __restrict__ bcur) {
    int b = blockIdx.x * blockDim.x + threadIdx.x;
    if (b < NB) bcur[b * 16] = offs[b << 7];
}

// stage 1: bin edges by dst>>7; pack (src | dloc<<16, ea) into bedge
__global__ void bscatter_k(const int* __restrict__ ei, const float* __restrict__ ea,
                           int* __restrict__ bcur, int2* __restrict__ bedge) {
    int e = blockIdx.x * blockDim.x + threadIdx.x;
    if (e >= N_EDGES) return;
    int src = ei[e], dst = ei[N_EDGES + e];
    int b = dst >> 7;
    int pos = atomicAdd(&bcur[b * 16], 1);
    int2 p;
    p.x = src | ((dst & 127) << 16);
    p.y = __float_as_int(ea[e]);
    bedge[pos] = p;
}

// stage 2: one block per bucket; scatter to exact CSR position (block-local 32KB region)
__global__ void bsort_k(const int* __restrict__ offs, const int2* __restrict__ bedge,
                        int* __restrict__ cursor, int2* __restrict__ csr) {
    int b = blockIdx.x;
    int beg = offs[b << 7];
    int endn = (b + 1) << 7; if (endn > N_NODES) endn = N_NODES;
    int end = offs[endn];
    for (int i = beg + threadIdx.x; i < end; i += blockDim.x) {
        int2 p = bedge[i];
        int dst = (b << 7) | (p.x >> 16);
        int pos = atomicAdd(&cursor[dst], 1);
        int2 q; q.x = p.x & 0xFFFF; q.y = p.y;
        csr[pos] = q;
    }
}

// ---------------- per-layer kernels ----------------
__global__ void node_k(const float* __restrict__ h, const float* __restrict__ ws, int l,
                       float* __restrict__ hA, float* __restrict__ hB) {
    __shared__ float sA[1024], sB[1024];
    const float* W1A = ws + W1A_OFF + l * 1024;
    const float* W1B = ws + W1B_OFF + l * 1024;
    for (int i = threadIdx.x; i < 1024; i += blockDim.x) { sA[i] = W1A[i]; sB[i] = W1B[i]; }
    __syncthreads();
    int t = blockIdx.x * blockDim.x + threadIdx.x;
    if (t >= NODE_F) return;
    int j = t & 31;
    float hv = h[t];
    float a = ws[C1_OFF + l * 32 + j];
    float b = 0.f;
#pragma unroll
    for (int k = 0; k < 32; ++k) {
        float hk = __shfl(hv, k, 32);
        a += hk * sA[k * 32 + j];
        b += hk * sB[k * 32 + j];
    }
    hA[t] = a;
    hB[t] = b;
}

// One wave per node; 32 edges per iteration (2 A-frags, 4 MFMAs) for gather ILP.
// A frag: lane l = row l&15, k = 8*(l>>4)+i. C/D: col=lane&15, row=4*(lane>>4)+reg.
__launch_bounds__(256)
__global__ void edge_mfma_k(const int* __restrict__ offs, const int2* __restrict__ csr,
                            const float* __restrict__ ws, int l,
                            const float* __restrict__ h, const float* __restrict__ hA,
                            const float* __restrict__ hB, float* __restrict__ hnext) {
    const int lane = threadIdx.x & 63;
    const int n = blockIdx.x * 4 + (threadIdx.x >> 6);
    if (n >= N_NODES) return;
    const int r = lane & 15;   // A row / D col
    const int q = lane >> 4;   // channel octet

    const float* W2p = ws + W2_OFF + l * 1024;
    BF8 b0, b1;
#pragma unroll
    for (int i = 0; i < 8; ++i) {
        b0.us[i] = f2bf(W2p[(8 * q + i) * 32 + r]);
        b1.us[i] = f2bf(W2p[(8 * q + i) * 32 + 16 + r]);
    }
    const float c2a = ws[C2_OFF + l * 32 + r];
    const float c2b = ws[C2_OFF + l * 32 + 16 + r];
    const f32x4 hA0 = *(const f32x4*)(hA + n * 32 + 8 * q);
    const f32x4 hA1 = *(const f32x4*)(hA + n * 32 + 8 * q + 4);
    const f32x4 we0 = *(const f32x4*)(ws + WE_OFF + l * 32 + 8 * q);
    const f32x4 we1 = *(const f32x4*)(ws + WE_OFF + l * 32 + 8 * q + 4);

    const int beg = offs[n], end = offs[n + 1];
    float ns0 = 0.f, ns1 = 0.f;

    for (int ebase = beg; ebase < end; ebase += 32) {
        const int last = end - 1;
        int e0 = ebase + r;       e0 = (e0 < last) ? e0 : last;
        int e1 = ebase + 16 + r;  e1 = (e1 < last) ? e1 : last;
        int2 p0 = csr[e0];
        int2 p1 = csr[e1];
        int s0 = p0.x; float ea0 = __int_as_float(p0.y);
        int s1 = p1.x; float ea1 = __int_as_float(p1.y);
        const f32x4 hb00 = *(const f32x4*)(hB + s0 * 32 + 8 * q);
        const f32x4 hb01 = *(const f32x4*)(hB + s0 * 32 + 8 * q + 4);
        const f32x4 hb10 = *(const f32x4*)(hB + s1 * 32 + 8 * q);
        const f32x4 hb11 = *(const f32x4*)(hB + s1 * 32 + 8 * q + 4);
        BF8 a0, a1;
#pragma unroll
        for (int i = 0; i < 4; ++i) {
            a0.us[i]     = f2bf(fmaxf(hA0[i] + hb00[i] + ea0 * we0[i], 0.f));
            a0.us[i + 4] = f2bf(fmaxf(hA1[i] + hb01[i] + ea0 * we1[i], 0.f));
            a1.us[i]     = f2bf(fmaxf(hA0[i] + hb10[i] + ea1 * we0[i], 0.f));
            a1.us[i + 4] = f2bf(fmaxf(hA1[i] + hb11[i] + ea1 * we1[i], 0.f));
        }
        f32x4 z = {0.f, 0.f, 0.f, 0.f};
        f32x4 acc00 = __builtin_amdgcn_mfma_f32_16x16x32_bf16(a0.v, b0.v, z, 0, 0, 0);
        f32x4 acc01 = __builtin_amdgcn_mfma_f32_16x16x32_bf16(a0.v, b1.v, z, 0, 0, 0);
        f32x4 acc10 = __builtin_amdgcn_mfma_f32_16x16x32_bf16(a1.v, b0.v, z, 0, 0, 0);
        f32x4 acc11 = __builtin_amdgcn_mfma_f32_16x16x32_bf16(a1.v, b1.v, z, 0, 0, 0);
        int nreal = end - ebase;
#pragma unroll
        for (int reg = 0; reg < 4; ++reg) {
            int row = 4 * q + reg;
            ns0 += (row < nreal) ? fmaxf(acc00[reg] + c2a, 0.f) : 0.f;
            ns1 += (row < nreal) ? fmaxf(acc01[reg] + c2b, 0.f) : 0.f;
            ns0 += (row + 16 < nreal) ? fmaxf(acc10[reg] + c2a, 0.f) : 0.f;
            ns1 += (row + 16 < nreal) ? fmaxf(acc11[reg] + c2b, 0.f) : 0.f;
        }
    }
    ns0 += __shfl_xor(ns0, 16, 64);
    ns0 += __shfl_xor(ns0, 32, 64);
    ns1 += __shfl_xor(ns1, 16, 64);
    ns1 += __shfl_xor(ns1, 32, 64);
    if (lane < 32) {
        float base = h[n * 32 + lane];
        hnext[n * 32 + lane] = base + ((lane & 16) ? ns1 : ns0);
    }
}

__global__ void head_k(const float* __restrict__ h, const int* __restrict__ cand,
                       const int* __restrict__ batch, const float* __restrict__ Wout,
                       const float* __restrict__ bout, float* __restrict__ out) {
    __shared__ float Lg[N_CAND];
    __shared__ int Sg[N_CAND];
    __shared__ float gm[N_GRAPHS], gs[N_GRAPHS];
    int t = threadIdx.x;  // 1024
    if (t < N_CAND) {
        int c = cand[t];
        float acc = bout[0];
#pragma unroll
        for (int j = 0; j < 32; ++j) acc += h[c * 32 + j] * Wout[j];
        Lg[t] = acc;
        Sg[t] = batch[c];
    }
    __syncthreads();
    if (t < 16 * N_GRAPHS) {
        int g = t >> 4, s = t & 15;
        float m = -1e30f;
        for (int i = s; i < N_CAND; i += 16)
            if (Sg[i] == g) m = fmaxf(m, Lg[i]);
#pragma unroll
        for (int d = 1; d < 16; d <<= 1) m = fmaxf(m, __shfl_xor(m, d, 64));
        float ssum = 0.f;
        for (int i = s; i < N_CAND; i += 16)
            if (Sg[i] == g) ssum += expf(Lg[i] - m);
#pragma unroll
        for (int d = 1; d < 16; d <<= 1) ssum += __shfl_xor(ssum, d, 64);
        if (s == 0) { gm[g] = m; gs[g] = logf(ssum); }
    }
    __syncthreads();
    if (t < N_CAND) out[t] = Lg[t] - gm[Sg[t]] - gs[Sg[t]];
}

extern "C" void kernel_launch(void* const* d_in, const int* in_sizes, int n_in,
                              void* d_out, int out_size, void* d_ws, size_t ws_size,
                              hipStream_t stream) {
    const float* x    = (const float*)d_in[0];
    const int*   ei   = (const int*)d_in[1];
    const float* eatt = (const float*)d_in[2];
    const int*   cand = (const int*)d_in[3];
    const int*   batch= (const int*)d_in[4];
    const float* Win  = (const float*)d_in[5];
    const float* bin  = (const float*)d_in[6];
    const float* W1   = (const float*)d_in[7];
    const float* b1   = (const float*)d_in[8];
    const float* g1   = (const float*)d_in[9];
    const float* be1  = (const float*)d_in[10];
    const float* m1   = (const float*)d_in[11];
    const float* v1   = (const float*)d_in[12];
    const float* W2   = (const float*)d_in[13];
    const float* b2   = (const float*)d_in[14];
    const float* g2   = (const float*)d_in[15];
    const float* be2  = (const float*)d_in[16];
    const float* m2   = (const float*)d_in[17];
    const float* v2   = (const float*)d_in[18];
    const float* Wout = (const float*)d_in[19];
    const float* bout = (const float*)d_in[20];
    float* out = (float*)d_out;
    float* ws = (float*)d_ws;

    float* h0 = ws + H_OFF;
    float* h1 = ws + H_OFF + NODE_F;
    float* hA = ws + H_OFF + 2 * NODE_F;
    float* hB = ws + H_OFF + 3 * NODE_F;
    int* deg    = (int*)(ws + DEG_OFF);
    int* offs   = (int*)(ws + OFFS_OFF);
    int* cursor = (int*)(ws + CUR_OFF);
    int* part   = (int*)(ws + PART_OFF);
    int* bcur   = (int*)(ws + BCUR_OFF);
    int2* csr   = (int2*)(ws + CSR_OFF);
    int2* bedge = (int2*)(ws + H_OFF + 2 * NODE_F);  // aliases hA/hB (used before node_k)

    prep_k<<<1, 256, 0, stream>>>(W1, b1, g1, be1, m1, v1, W2, b2, g2, be2, m2, v2, ws);
    embed_k<<<(NODE_F + 255) / 256, 256, 0, stream>>>(x, Win, bin, h0);

    const int SCAN_B = (N_NODES + 1023) / 1024;  // 49
    zero_k<<<(N_NODES + 255) / 256, 256, 0, stream>>>(deg, N_NODES);
    hist_k<<<(N_EDGES + 255) / 256, 256, 0, stream>>>(ei, deg);
    scan1_k<<<SCAN_B, 1024, 0, stream>>>(deg, offs, part);
    scan2_k<<<1, 64, 0, stream>>>(part, SCAN_B);
    scan3_k<<<SCAN_B, 1024, 0, stream>>>(offs, part, cursor);
    binit_k<<<(NB + 255) / 256, 256, 0, stream>>>(offs, bcur);
    bscatter_k<<<(N_EDGES + 255) / 256, 256, 0, stream>>>(ei, eatt, bcur, bedge);
    bsort_k<<<NB, 256, 0, stream>>>(offs, bedge, cursor, csr);

    float* cur = h0;
    float* nxt = h1;
    for (int l = 0; l < L_LAYERS; ++l) {
        node_k<<<(NODE_F + 255) / 256, 256, 0, stream>>>(cur, ws, l, hA, hB);
        edge_mfma_k<<<(N_NODES + 3) / 4, 256, 0, stream>>>(offs, csr, ws, l,
                                                           cur, hA, hB, nxt);
        float* tmp = cur; cur = nxt; nxt = tmp;
    }

    head_k<<<1, 1024, 0, stream>>>(cur, cand, batch, Wout, bout, out);
}